// Round 1
// baseline (8705.061 us; speedup 1.0000x reference)
//
#include <hip/hip_runtime.h>
#include <math.h>

typedef unsigned short u16;
typedef unsigned int u32;

typedef short bf16x8 __attribute__((ext_vector_type(8)));
typedef float f32x4 __attribute__((ext_vector_type(4)));
typedef __attribute__((address_space(1))) const void gconst_t;
typedef __attribute__((address_space(3))) void lds_t;

__device__ __forceinline__ float bf2f(u16 u) {
  union { u32 i; float f; } v; v.i = ((u32)u) << 16; return v.f;
}
__device__ __forceinline__ u16 f2bf(float f) {
  union { float f; u32 i; } v; v.f = f;
  u32 r = v.i + 0x7fffu + ((v.i >> 16) & 1u);   // RNE
  return (u16)(r >> 16);
}

// ---------------------------------------------------------------------------
// Row LayerNorm over D=1280, block=320 threads (5 waves), one row per block.
// w/b may be null (pure normalize). OutT = u16 (bf16) or float.
// ---------------------------------------------------------------------------
__device__ __forceinline__ void store4(float* p, float4 y) { *(float4*)p = y; }
__device__ __forceinline__ void store4(u16* p, float4 y) {
  ushort4 u; u.x = f2bf(y.x); u.y = f2bf(y.y); u.z = f2bf(y.z); u.w = f2bf(y.w);
  *(ushort4*)p = u;
}

template <typename OutT>
__global__ __launch_bounds__(320) void ln_rows(const float* __restrict__ in,
    OutT* __restrict__ out, const float* __restrict__ w, const float* __restrict__ b)
{
  __shared__ float ps[5], pss[5];
  const int row = blockIdx.x, t = threadIdx.x;
  const float4 x = ((const float4*)(in + (size_t)row * 1280))[t];
  float s = x.x + x.y + x.z + x.w;
  float ss = x.x * x.x + x.y * x.y + x.z * x.z + x.w * x.w;
#pragma unroll
  for (int o = 32; o > 0; o >>= 1) { s += __shfl_xor(s, o); ss += __shfl_xor(ss, o); }
  if ((t & 63) == 0) { ps[t >> 6] = s; pss[t >> 6] = ss; }
  __syncthreads();
  s = ps[0] + ps[1] + ps[2] + ps[3] + ps[4];
  ss = pss[0] + pss[1] + pss[2] + pss[3] + pss[4];
  const float mean = s * (1.f / 1280.f);
  const float rstd = rsqrtf(ss * (1.f / 1280.f) - mean * mean + 1e-5f);
  float4 y;
  y.x = (x.x - mean) * rstd; y.y = (x.y - mean) * rstd;
  y.z = (x.z - mean) * rstd; y.w = (x.w - mean) * rstd;
  if (w) {
    const float4 wv4 = ((const float4*)w)[t];
    const float4 bv4 = ((const float4*)b)[t];
    y.x = y.x * wv4.x + bv4.x; y.y = y.y * wv4.y + bv4.y;
    y.z = y.z * wv4.z + bv4.z; y.w = y.w * wv4.w + bv4.w;
  }
  store4(out + (size_t)row * 1280 + t * 4, y);
}

// lat[r][:] = latents[r & 63][:]
__global__ __launch_bounds__(320) void lat_init(const float* __restrict__ latents,
                                                float* __restrict__ lat)
{
  const int r = blockIdx.x, t = threadIdx.x;
  ((float4*)(lat + (size_t)r * 1280))[t] =
      ((const float4*)(latents + (size_t)(r & 63) * 1280))[t];
}

// dst[n][k] = src[k][n] * (fold ? fold[k] : 1), cast to bf16. 32x32 LDS tiles.
__global__ __launch_bounds__(256) void transcast(const float* __restrict__ src,
    u16* __restrict__ dst, const float* __restrict__ fold, int K, int N)
{
  __shared__ float tile[32][33];
  const int n0 = blockIdx.x * 32, k0 = blockIdx.y * 32;
  const int tx = threadIdx.x & 31, ty = threadIdx.x >> 5;
#pragma unroll
  for (int r = ty; r < 32; r += 8) {
    float v = src[(size_t)(k0 + r) * N + n0 + tx];
    if (fold) v *= fold[k0 + r];
    tile[r][tx] = v;
  }
  __syncthreads();
#pragma unroll
  for (int r = ty; r < 32; r += 8)
    dst[(size_t)(n0 + r) * K + k0 + tx] = f2bf(tile[tx][r]);
}

// out[h] = sum_d bvec[d] * wT[h][d]   (wT bf16 [N][K])
__global__ __launch_bounds__(64) void bias_dot(const u16* __restrict__ wT,
    const float* __restrict__ bvec, float* __restrict__ outp, int K)
{
  const int h = blockIdx.x, lane = threadIdx.x;
  const u16* row = wT + (size_t)h * K;
  float s = 0.f;
  for (int i = lane; i < K; i += 64) s += bvec[i] * bf2f(row[i]);
#pragma unroll
  for (int o = 32; o > 0; o >>= 1) s += __shfl_xor(s, o);
  if (lane == 0) outp[h] = s;
}

// ---------------------------------------------------------------------------
// In-place LayerNorm over contiguous 96-element segments (q/k head-dim LN),
// bf16 storage, fused scale. One wave per segment, 4 segments per block.
// ---------------------------------------------------------------------------
__global__ __launch_bounds__(256) void seg_ln(u16* __restrict__ buf,
    const float* __restrict__ w, const float* __restrict__ b, float scale, int nseg)
{
  const int seg = blockIdx.x * 4 + (threadIdx.x >> 6);
  if (seg >= nseg) return;
  const int lane = threadIdx.x & 63;
  u16* p = buf + (size_t)seg * 96;
  const float a = bf2f(p[lane]);
  const float c = (lane < 32) ? bf2f(p[64 + lane]) : 0.f;
  float s = a + c, ss = a * a + c * c;
#pragma unroll
  for (int o = 32; o > 0; o >>= 1) { s += __shfl_xor(s, o); ss += __shfl_xor(ss, o); }
  const float mean = s * (1.f / 96.f);
  const float rstd = rsqrtf(ss * (1.f / 96.f) - mean * mean + 1e-5f);
  p[lane] = f2bf(((a - mean) * rstd * w[lane] + b[lane]) * scale);
  if (lane < 32)
    p[64 + lane] = f2bf(((c - mean) * rstd * w[64 + lane] + b[64 + lane]) * scale);
}

// ---------------------------------------------------------------------------
// bf16 MFMA GEMM, m97 pattern: C[M,N] = A[M,K] @ BT[N,K]^T (+bias)(+resid)
// 128x128 tile, BK=64, global_load_lds(16B) staging, mfma_f32_16x16x32_bf16.
// out_row = (in_row >> sh)*bstride + off + (in_row & ((1<<sh)-1))
// flags: 1 = bf16 output, 2 = relu. resid (fp32) indexed [out_row*N + col].
// ---------------------------------------------------------------------------
#define GTM 128
#define GTN 128
#define GBK 64

__global__ __launch_bounds__(256) void gemm_bf16(
    const u16* __restrict__ A, const u16* __restrict__ BT,
    void* Cp, const float* __restrict__ bias, const float* resid,
    int M, int N, int K, int sh, int bstride, int off, int flags)
{
  __shared__ __align__(16) u16 As[GTM * GBK];
  __shared__ __align__(16) u16 Bs[GTN * GBK];
  const int tid = threadIdx.x;
  const int lane = tid & 63;
  const int wv = tid >> 6;
  const int m0 = blockIdx.y * GTM;
  const int n0 = blockIdx.x * GTN;
  const int wm = (wv >> 1) * 64;
  const int wn = (wv & 1) * 64;
  const int srow = lane >> 3;
  const int scol = (lane & 7) * 8;

  f32x4 acc[4][4] = {};

  const u16* Ab = A + (size_t)m0 * K;
  const u16* Bb = BT + (size_t)n0 * K;

  for (int kt = 0; kt < K; kt += GBK) {
#pragma unroll
    for (int it = 0; it < 4; ++it) {
      const int r = wv * 32 + it * 8;
      const u16* ga = Ab + (size_t)(r + srow) * K + kt + scol;
      __builtin_amdgcn_global_load_lds((gconst_t*)ga, (lds_t*)(As + r * GBK), 16, 0, 0);
      const u16* gb = Bb + (size_t)(r + srow) * K + kt + scol;
      __builtin_amdgcn_global_load_lds((gconst_t*)gb, (lds_t*)(Bs + r * GBK), 16, 0, 0);
    }
    __syncthreads();
#pragma unroll
    for (int ks = 0; ks < GBK; ks += 32) {
      bf16x8 af[4], bfr[4];
      const int koff = ks + ((lane >> 4) << 3);
      const int rsel = lane & 15;
#pragma unroll
      for (int f = 0; f < 4; ++f)
        af[f] = *(const bf16x8*)(As + (wm + f * 16 + rsel) * GBK + koff);
#pragma unroll
      for (int f = 0; f < 4; ++f)
        bfr[f] = *(const bf16x8*)(Bs + (wn + f * 16 + rsel) * GBK + koff);
#pragma unroll
      for (int fm = 0; fm < 4; ++fm)
#pragma unroll
        for (int fn = 0; fn < 4; ++fn)
          acc[fm][fn] = __builtin_amdgcn_mfma_f32_16x16x32_bf16(
              af[fm], bfr[fn], acc[fm][fn], 0, 0, 0);
    }
    __syncthreads();
  }

  const int colb = n0 + wn + (lane & 15);
  const int rowb = m0 + wm + ((lane >> 4) << 2);
  const int msk = (1 << sh) - 1;
  const bool obf = flags & 1;
  const bool rel = flags & 2;
#pragma unroll
  for (int fm = 0; fm < 4; ++fm) {
#pragma unroll
    for (int r = 0; r < 4; ++r) {
      const int ir = rowb + fm * 16 + r;
      const size_t orow = (size_t)((ir >> sh) * bstride + off + (ir & msk));
#pragma unroll
      for (int fn = 0; fn < 4; ++fn) {
        const int col = colb + fn * 16;
        float v = acc[fm][fn][r];
        if (bias) v += bias[col];
        if (rel) v = fmaxf(v, 0.f);
        if (resid) v += resid[orow * N + col];
        if (obf) ((u16*)Cp)[orow * N + col] = f2bf(v);
        else ((float*)Cp)[orow * N + col] = v;
      }
    }
  }
}

// ---------------------------------------------------------------------------
// Flash attention: one block per (h=blockIdx.x, b=blockIdx.y). 256 threads.
// Q/K/V bf16; Q pre-LN'd & pre-scaled; K pre-LN'd. 33 tiles of 64 kv rows.
// Thread (qr = t>>3 in 0..31, g = t&7): rows (qr, qr+32), d-slice g*12..+11.
// ---------------------------------------------------------------------------
__global__ __launch_bounds__(256) void attn_kernel(
    const u16* __restrict__ Q, const u16* __restrict__ Kb,
    const u16* __restrict__ Vb, u16* __restrict__ Res)
{
  const int h = blockIdx.x, b = blockIdx.y;
  __shared__ __align__(16) float Ks[64][96];
  __shared__ __align__(16) float Vs[64][96];
  const int t = threadIdx.x;
  const int lane = t & 63;
  const int g = t & 7;
  const int qr = t >> 3;

  float q0[12], q1[12], O0[12], O1[12];
  const size_t qoff = (size_t)(b * 64 + qr) * 1536 + h * 96 + g * 12;
#pragma unroll
  for (int i = 0; i < 12; ++i) {
    q0[i] = bf2f(Q[qoff + i]);
    q1[i] = bf2f(Q[qoff + 32 * 1536 + i]);
    O0[i] = 0.f; O1[i] = 0.f;
  }
  float m0 = -1e30f, m1 = -1e30f, l0 = 0.f, l1 = 0.f;
  const size_t kbase = (size_t)b * 2112 * 1536 + (size_t)h * 96;

  for (int tile = 0; tile < 33; ++tile) {
    __syncthreads();
    for (int i = t; i < 64 * 48; i += 256) {
      const int j = i / 48, d2 = i - j * 48;
      const size_t ga = kbase + (size_t)(tile * 64 + j) * 1536 + d2 * 2;
      const u32 kw = *(const u32*)(Kb + ga);
      const u32 vw = *(const u32*)(Vb + ga);
      Ks[j][d2 * 2] = bf2f((u16)(kw & 0xffffu));
      Ks[j][d2 * 2 + 1] = bf2f((u16)(kw >> 16));
      Vs[j][d2 * 2] = bf2f((u16)(vw & 0xffffu));
      Vs[j][d2 * 2 + 1] = bf2f((u16)(vw >> 16));
    }
    __syncthreads();

    float sr0[8], sr1[8];
#pragma unroll
    for (int jo = 0; jo < 8; ++jo) {
      sr0[jo] = 0.f; sr1[jo] = 0.f;
      for (int ji = 0; ji < 8; ++ji) {
        const int jj = jo * 8 + ji;
        const float4* kr = (const float4*)&Ks[jj][g * 12];
        const float4 ka = kr[0], kb4 = kr[1], kc = kr[2];
        float p0 = q0[0]*ka.x + q0[1]*ka.y + q0[2]*ka.z + q0[3]*ka.w
                 + q0[4]*kb4.x + q0[5]*kb4.y + q0[6]*kb4.z + q0[7]*kb4.w
                 + q0[8]*kc.x + q0[9]*kc.y + q0[10]*kc.z + q0[11]*kc.w;
        float p1 = q1[0]*ka.x + q1[1]*ka.y + q1[2]*ka.z + q1[3]*ka.w
                 + q1[4]*kb4.x + q1[5]*kb4.y + q1[6]*kb4.z + q1[7]*kb4.w
                 + q1[8]*kc.x + q1[9]*kc.y + q1[10]*kc.z + q1[11]*kc.w;
        p0 += __shfl_xor(p0, 1); p1 += __shfl_xor(p1, 1);
        p0 += __shfl_xor(p0, 2); p1 += __shfl_xor(p1, 2);
        p0 += __shfl_xor(p0, 4); p1 += __shfl_xor(p1, 4);
        if (ji == g) { sr0[jo] = p0; sr1[jo] = p1; }
      }
    }

    float mt0 = sr0[0], mt1 = sr1[0];
#pragma unroll
    for (int i = 1; i < 8; ++i) { mt0 = fmaxf(mt0, sr0[i]); mt1 = fmaxf(mt1, sr1[i]); }
    mt0 = fmaxf(mt0, __shfl_xor(mt0, 1)); mt1 = fmaxf(mt1, __shfl_xor(mt1, 1));
    mt0 = fmaxf(mt0, __shfl_xor(mt0, 2)); mt1 = fmaxf(mt1, __shfl_xor(mt1, 2));
    mt0 = fmaxf(mt0, __shfl_xor(mt0, 4)); mt1 = fmaxf(mt1, __shfl_xor(mt1, 4));
    const float nm0 = fmaxf(m0, mt0), nm1 = fmaxf(m1, mt1);
    const float a0 = __expf(m0 - nm0), a1 = __expf(m1 - nm1);
    float pr0[8], pr1[8];
    float s0 = 0.f, s1 = 0.f;
#pragma unroll
    for (int i = 0; i < 8; ++i) {
      pr0[i] = __expf(sr0[i] - nm0); s0 += pr0[i];
      pr1[i] = __expf(sr1[i] - nm1); s1 += pr1[i];
    }
    s0 += __shfl_xor(s0, 1); s1 += __shfl_xor(s1, 1);
    s0 += __shfl_xor(s0, 2); s1 += __shfl_xor(s1, 2);
    s0 += __shfl_xor(s0, 4); s1 += __shfl_xor(s1, 4);
    l0 = l0 * a0 + s0; l1 = l1 * a1 + s1;
    m0 = nm0; m1 = nm1;
#pragma unroll
    for (int i = 0; i < 12; ++i) { O0[i] *= a0; O1[i] *= a1; }

#pragma unroll
    for (int jo = 0; jo < 8; ++jo) {
      for (int ji = 0; ji < 8; ++ji) {
        const int jj = jo * 8 + ji;
        const int src = (lane & 56) | ji;
        const float pv0 = __shfl(pr0[jo], src);
        const float pv1 = __shfl(pr1[jo], src);
        const float4* vr = (const float4*)&Vs[jj][g * 12];
        const float4 va = vr[0], vb4 = vr[1], vc = vr[2];
        O0[0] += pv0 * va.x;  O0[1] += pv0 * va.y;  O0[2]  += pv0 * va.z;  O0[3]  += pv0 * va.w;
        O0[4] += pv0 * vb4.x; O0[5] += pv0 * vb4.y; O0[6]  += pv0 * vb4.z; O0[7]  += pv0 * vb4.w;
        O0[8] += pv0 * vc.x;  O0[9] += pv0 * vc.y;  O0[10] += pv0 * vc.z;  O0[11] += pv0 * vc.w;
        O1[0] += pv1 * va.x;  O1[1] += pv1 * va.y;  O1[2]  += pv1 * va.z;  O1[3]  += pv1 * va.w;
        O1[4] += pv1 * vb4.x; O1[5] += pv1 * vb4.y; O1[6]  += pv1 * vb4.z; O1[7]  += pv1 * vb4.w;
        O1[8] += pv1 * vc.x;  O1[9] += pv1 * vc.y;  O1[10] += pv1 * vc.z;  O1[11] += pv1 * vc.w;
      }
    }
  }

  const float il0 = 1.f / l0, il1 = 1.f / l1;
#pragma unroll
  for (int i = 0; i < 12; ++i) {
    Res[qoff + i] = f2bf(O0[i] * il0);
    Res[qoff + 32 * 1536 + i] = f2bf(O1[i] * il1);
  }
}

// ---------------------------------------------------------------------------
extern "C" void kernel_launch(void* const* d_in, const int* in_sizes, int n_in,
                              void* d_out, int out_size, void* d_ws, size_t ws_size,
                              hipStream_t stream) {
  const float* context  = (const float*)d_in[0];
  const float* latents  = (const float*)d_in[1];
  const float* ctx_ln_w = (const float*)d_in[2];
  const float* ctx_ln_b = (const float*)d_in[3];
  const float* lat_ln_w = (const float*)d_in[4];
  const float* lat_ln_b = (const float*)d_in[5];
  const float* q_ln_w   = (const float*)d_in[6];
  const float* q_ln_b   = (const float*)d_in[7];
  const float* k_ln_w   = (const float*)d_in[8];
  const float* k_ln_b   = (const float*)d_in[9];
  const float* wq       = (const float*)d_in[10];
  const float* wk       = (const float*)d_in[11];
  const float* wv       = (const float*)d_in[12];
  const float* wo       = (const float*)d_in[13];
  const float* mlp_ln_w = (const float*)d_in[14];
  const float* mlp_ln_b = (const float*)d_in[15];
  const float* w_fc     = (const float*)d_in[16];
  const float* w_cproj  = (const float*)d_in[17];
  const float* fin_w    = (const float*)d_in[18];
  const float* fin_b    = (const float*)d_in[19];

  char* ws = (char*)d_ws;
  u16*   normctx = (u16*)(ws + 0ull);            // [65536,1280] bf16
  u16*   Kbuf    = (u16*)(ws + 167772160ull);    // [32,2112,1536] bf16
  u16*   Vbuf    = (u16*)(ws + 375390208ull);    // [32,2112,1536] bf16
  float* lat     = (float*)(ws + 583008256ull);  // [2048,1280] f32
  u16*   latn    = (u16*)(ws + 593494016ull);    // [2048,1280] bf16
  u16*   mlpn    = (u16*)(ws + 598736896ull);    // [2048,1280] bf16
  u16*   qb      = (u16*)(ws + 603979776ull);    // [2048,1536] bf16
  u16*   res     = (u16*)(ws + 610271232ull);    // [2048,1536] bf16
  u16*   hb      = (u16*)(ws + 616562688ull);    // [2048,5120] bf16
  u16*   wT      = (u16*)(ws + 637534208ull);    // per-layer transposed weights
  float* biask   = (float*)(ws + 687341568ull);  // [1536]
  float* biasv   = biask + 1536;

  u16* wqT  = wT;
  u16* wkT  = wT + 1966080;
  u16* wvT  = wT + 3932160;
  u16* wkfT = wT + 5898240;
  u16* wvfT = wT + 7864320;
  u16* woT  = wT + 9830400;
  u16* wfcT = wT + 11796480;
  u16* wcpT = wT + 18350080;

  const float qscale = 1.0f / sqrtf(96.0f);

  // norm(context) once: layer-invariant (ctx LN w/b folded into weights)
  ln_rows<u16><<<65536, 320, 0, stream>>>(context, normctx, nullptr, nullptr);
  lat_init<<<2048, 320, 0, stream>>>(latents, lat);

  for (int i = 0; i < 3; ++i) {
    transcast<<<dim3(48, 40), 256, 0, stream>>>(wq + (size_t)i * 1966080, wqT, nullptr, 1280, 1536);
    transcast<<<dim3(48, 40), 256, 0, stream>>>(wk + (size_t)i * 1966080, wkT, nullptr, 1280, 1536);
    transcast<<<dim3(48, 40), 256, 0, stream>>>(wv + (size_t)i * 1966080, wvT, nullptr, 1280, 1536);
    transcast<<<dim3(48, 40), 256, 0, stream>>>(wk + (size_t)i * 1966080, wkfT, ctx_ln_w + i * 1280, 1280, 1536);
    transcast<<<dim3(48, 40), 256, 0, stream>>>(wv + (size_t)i * 1966080, wvfT, ctx_ln_w + i * 1280, 1280, 1536);
    transcast<<<dim3(40, 48), 256, 0, stream>>>(wo + (size_t)i * 1966080, woT, nullptr, 1536, 1280);
    transcast<<<dim3(160, 40), 256, 0, stream>>>(w_fc + (size_t)i * 6553600, wfcT, nullptr, 1280, 5120);
    transcast<<<dim3(40, 160), 256, 0, stream>>>(w_cproj + (size_t)i * 6553600, wcpT, nullptr, 5120, 1280);
    bias_dot<<<1536, 64, 0, stream>>>(wkT, ctx_ln_b + i * 1280, biask, 1280);
    bias_dot<<<1536, 64, 0, stream>>>(wvT, ctx_ln_b + i * 1280, biasv, 1280);

    ln_rows<u16><<<2048, 320, 0, stream>>>(lat, latn, lat_ln_w + i * 1280, lat_ln_b + i * 1280);

    // K/V: ctx part (rows b*2112+s) + latent part (rows b*2112+2048+n)
    gemm_bf16<<<dim3(12, 512), 256, 0, stream>>>(normctx, wkfT, Kbuf, biask, nullptr,
        65536, 1536, 1280, 11, 2112, 0, 1);
    gemm_bf16<<<dim3(12, 16), 256, 0, stream>>>(latn, wkT, Kbuf, nullptr, nullptr,
        2048, 1536, 1280, 6, 2112, 2048, 1);
    gemm_bf16<<<dim3(12, 512), 256, 0, stream>>>(normctx, wvfT, Vbuf, biasv, nullptr,
        65536, 1536, 1280, 11, 2112, 0, 1);
    gemm_bf16<<<dim3(12, 16), 256, 0, stream>>>(latn, wvT, Vbuf, nullptr, nullptr,
        2048, 1536, 1280, 6, 2112, 2048, 1);
    // Q
    gemm_bf16<<<dim3(12, 16), 256, 0, stream>>>(latn, wqT, qb, nullptr, nullptr,
        2048, 1536, 1280, 11, 2048, 0, 1);

    // per-head LN on q (with qk_scale folded) and k
    seg_ln<<<8192, 256, 0, stream>>>(qb, q_ln_w + i * 96, q_ln_b + i * 96, qscale, 32768);
    seg_ln<<<270336, 256, 0, stream>>>(Kbuf, k_ln_w + i * 96, k_ln_b + i * 96, 1.0f, 1081344);

    attn_kernel<<<dim3(16, 32), 256, 0, stream>>>(qb, Kbuf, Vbuf, res);

    // lat = res @ wo + lat
    gemm_bf16<<<dim3(10, 16), 256, 0, stream>>>(res, woT, lat, nullptr, lat,
        2048, 1280, 1536, 11, 2048, 0, 0);

    // MLP
    ln_rows<u16><<<2048, 320, 0, stream>>>(lat, mlpn, mlp_ln_w + i * 1280, mlp_ln_b + i * 1280);
    gemm_bf16<<<dim3(40, 16), 256, 0, stream>>>(mlpn, wfcT, hb, nullptr, nullptr,
        2048, 5120, 1280, 11, 2048, 0, 1 | 2);
    gemm_bf16<<<dim3(10, 16), 256, 0, stream>>>(hb, wcpT, lat, nullptr, lat,
        2048, 1280, 5120, 11, 2048, 0, 0);
  }

  ln_rows<float><<<2048, 320, 0, stream>>>(lat, (float*)d_out, fin_w, fin_b);
}

// Round 2
// 6401.191 us; speedup vs baseline: 1.3599x; 1.3599x over previous
//
#include <hip/hip_runtime.h>
#include <math.h>

typedef unsigned short u16;
typedef unsigned int u32;

typedef short bf16x8 __attribute__((ext_vector_type(8)));
typedef unsigned short u16x8 __attribute__((ext_vector_type(8)));
typedef float f32x4 __attribute__((ext_vector_type(4)));
typedef __attribute__((address_space(1))) const void gconst_t;
typedef __attribute__((address_space(3))) void lds_t;

__device__ __forceinline__ float bf2f(u16 u) {
  union { u32 i; float f; } v; v.i = ((u32)u) << 16; return v.f;
}
__device__ __forceinline__ u16 f2bf(float f) {
  union { float f; u32 i; } v; v.f = f;
  u32 r = v.i + 0x7fffu + ((v.i >> 16) & 1u);   // RNE
  return (u16)(r >> 16);
}

// ---------------------------------------------------------------------------
// Row LayerNorm over D=1280, block=320 threads (5 waves), one row per block.
// ---------------------------------------------------------------------------
__device__ __forceinline__ void store4(float* p, float4 y) { *(float4*)p = y; }
__device__ __forceinline__ void store4(u16* p, float4 y) {
  ushort4 u; u.x = f2bf(y.x); u.y = f2bf(y.y); u.z = f2bf(y.z); u.w = f2bf(y.w);
  *(ushort4*)p = u;
}

template <typename OutT>
__global__ __launch_bounds__(320) void ln_rows(const float* __restrict__ in,
    OutT* __restrict__ out, const float* __restrict__ w, const float* __restrict__ b)
{
  __shared__ float ps[5], pss[5];
  const int row = blockIdx.x, t = threadIdx.x;
  const float4 x = ((const float4*)(in + (size_t)row * 1280))[t];
  float s = x.x + x.y + x.z + x.w;
  float ss = x.x * x.x + x.y * x.y + x.z * x.z + x.w * x.w;
#pragma unroll
  for (int o = 32; o > 0; o >>= 1) { s += __shfl_xor(s, o); ss += __shfl_xor(ss, o); }
  if ((t & 63) == 0) { ps[t >> 6] = s; pss[t >> 6] = ss; }
  __syncthreads();
  s = ps[0] + ps[1] + ps[2] + ps[3] + ps[4];
  ss = pss[0] + pss[1] + pss[2] + pss[3] + pss[4];
  const float mean = s * (1.f / 1280.f);
  const float rstd = rsqrtf(ss * (1.f / 1280.f) - mean * mean + 1e-5f);
  float4 y;
  y.x = (x.x - mean) * rstd; y.y = (x.y - mean) * rstd;
  y.z = (x.z - mean) * rstd; y.w = (x.w - mean) * rstd;
  if (w) {
    const float4 wv4 = ((const float4*)w)[t];
    const float4 bv4 = ((const float4*)b)[t];
    y.x = y.x * wv4.x + bv4.x; y.y = y.y * wv4.y + bv4.y;
    y.z = y.z * wv4.z + bv4.z; y.w = y.w * wv4.w + bv4.w;
  }
  store4(out + (size_t)row * 1280 + t * 4, y);
}

// lat[r][:] = latents[r & 63][:]
__global__ __launch_bounds__(320) void lat_init(const float* __restrict__ latents,
                                                float* __restrict__ lat)
{
  const int r = blockIdx.x, t = threadIdx.x;
  ((float4*)(lat + (size_t)r * 1280))[t] =
      ((const float4*)(latents + (size_t)(r & 63) * 1280))[t];
}

// dst[n][k] = src[k][n] * (fold ? fold[k] : 1), cast to bf16. 32x32 LDS tiles.
__global__ __launch_bounds__(256) void transcast(const float* __restrict__ src,
    u16* __restrict__ dst, const float* __restrict__ fold, int K, int N)
{
  __shared__ float tile[32][33];
  const int n0 = blockIdx.x * 32, k0 = blockIdx.y * 32;
  const int tx = threadIdx.x & 31, ty = threadIdx.x >> 5;
#pragma unroll
  for (int r = ty; r < 32; r += 8) {
    float v = src[(size_t)(k0 + r) * N + n0 + tx];
    if (fold) v *= fold[k0 + r];
    tile[r][tx] = v;
  }
  __syncthreads();
#pragma unroll
  for (int r = ty; r < 32; r += 8)
    dst[(size_t)(n0 + r) * K + k0 + tx] = f2bf(tile[tx][r]);
}

// out[h] = sum_d bvec[d] * wT[h][d]   (wT bf16 [N][K])
__global__ __launch_bounds__(64) void bias_dot(const u16* __restrict__ wT,
    const float* __restrict__ bvec, float* __restrict__ outp, int K)
{
  const int h = blockIdx.x, lane = threadIdx.x;
  const u16* row = wT + (size_t)h * K;
  float s = 0.f;
  for (int i = lane; i < K; i += 64) s += bvec[i] * bf2f(row[i]);
#pragma unroll
  for (int o = 32; o > 0; o >>= 1) s += __shfl_xor(s, o);
  if (lane == 0) outp[h] = s;
}

// ---------------------------------------------------------------------------
// In-place LayerNorm over contiguous 96-element segments (q/k head-dim LN).
// ---------------------------------------------------------------------------
__global__ __launch_bounds__(256) void seg_ln(u16* __restrict__ buf,
    const float* __restrict__ w, const float* __restrict__ b, float scale, int nseg)
{
  const int seg = blockIdx.x * 4 + (threadIdx.x >> 6);
  if (seg >= nseg) return;
  const int lane = threadIdx.x & 63;
  u16* p = buf + (size_t)seg * 96;
  const float a = bf2f(p[lane]);
  const float c = (lane < 32) ? bf2f(p[64 + lane]) : 0.f;
  float s = a + c, ss = a * a + c * c;
#pragma unroll
  for (int o = 32; o > 0; o >>= 1) { s += __shfl_xor(s, o); ss += __shfl_xor(ss, o); }
  const float mean = s * (1.f / 96.f);
  const float rstd = rsqrtf(ss * (1.f / 96.f) - mean * mean + 1e-5f);
  p[lane] = f2bf(((a - mean) * rstd * w[lane] + b[lane]) * scale);
  if (lane < 32)
    p[64 + lane] = f2bf(((c - mean) * rstd * w[64 + lane] + b[64 + lane]) * scale);
}

// ---------------------------------------------------------------------------
// bf16 MFMA GEMM, m97 pattern. C[M,N] = A[M,K] @ BT[N,K]^T (+bias)(+resid).
// flags: 1 = bf16 out, 2 = relu, 4 = column split at ldc (C0 then C1).
// out_row = (in_row >> sh)*bstride + off + (in_row & ((1<<sh)-1))
// ---------------------------------------------------------------------------
#define GTM 128
#define GTN 128
#define GBK 64

__global__ __launch_bounds__(256) void gemm_bf16(
    const u16* __restrict__ A, const u16* __restrict__ BT,
    void* C0, void* C1, const float* __restrict__ bias, const float* resid,
    int M, int N, int ldc, int K, int sh, int bstride, int off, int flags)
{
  __shared__ __align__(16) u16 As[GTM * GBK];
  __shared__ __align__(16) u16 Bs[GTN * GBK];
  const int tid = threadIdx.x;
  const int lane = tid & 63;
  const int wv = tid >> 6;
  const int m0 = blockIdx.y * GTM;
  const int n0 = blockIdx.x * GTN;
  const int wm = (wv >> 1) * 64;
  const int wn = (wv & 1) * 64;
  const int srow = lane >> 3;
  const int scol = (lane & 7) * 8;

  f32x4 acc[4][4] = {};

  const u16* Ab = A + (size_t)m0 * K;
  const u16* Bb = BT + (size_t)n0 * K;

  for (int kt = 0; kt < K; kt += GBK) {
#pragma unroll
    for (int it = 0; it < 4; ++it) {
      const int r = wv * 32 + it * 8;
      const u16* ga = Ab + (size_t)(r + srow) * K + kt + scol;
      __builtin_amdgcn_global_load_lds((gconst_t*)ga, (lds_t*)(As + r * GBK), 16, 0, 0);
      const u16* gb = Bb + (size_t)(r + srow) * K + kt + scol;
      __builtin_amdgcn_global_load_lds((gconst_t*)gb, (lds_t*)(Bs + r * GBK), 16, 0, 0);
    }
    __syncthreads();
#pragma unroll
    for (int ks = 0; ks < GBK; ks += 32) {
      bf16x8 af[4], bfr[4];
      const int koff = ks + ((lane >> 4) << 3);
      const int rsel = lane & 15;
#pragma unroll
      for (int f = 0; f < 4; ++f)
        af[f] = *(const bf16x8*)(As + (wm + f * 16 + rsel) * GBK + koff);
#pragma unroll
      for (int f = 0; f < 4; ++f)
        bfr[f] = *(const bf16x8*)(Bs + (wn + f * 16 + rsel) * GBK + koff);
#pragma unroll
      for (int fm = 0; fm < 4; ++fm)
#pragma unroll
        for (int fn = 0; fn < 4; ++fn)
          acc[fm][fn] = __builtin_amdgcn_mfma_f32_16x16x32_bf16(
              af[fm], bfr[fn], acc[fm][fn], 0, 0, 0);
    }
    __syncthreads();
  }

  const int colb = n0 + wn + (lane & 15);
  const int rowb = m0 + wm + ((lane >> 4) << 2);
  const int msk = (1 << sh) - 1;
  const bool obf = flags & 1;
  const bool rel = flags & 2;
  const bool spl = flags & 4;
#pragma unroll
  for (int fm = 0; fm < 4; ++fm) {
#pragma unroll
    for (int r = 0; r < 4; ++r) {
      const int ir = rowb + fm * 16 + r;
      const size_t orow = (size_t)((ir >> sh) * bstride + off + (ir & msk));
#pragma unroll
      for (int fn = 0; fn < 4; ++fn) {
        const int col = colb + fn * 16;
        float v = acc[fm][fn][r];
        if (bias) v += bias[col];
        if (rel) v = fmaxf(v, 0.f);
        void* cp = C0;
        int cl = col;
        if (spl && col >= ldc) { cp = C1; cl = col - ldc; }
        const size_t idx = orow * (size_t)ldc + cl;
        if (resid) v += resid[idx];
        if (obf) ((u16*)cp)[idx] = f2bf(v);
        else ((float*)cp)[idx] = v;
      }
    }
  }
}

// ---------------------------------------------------------------------------
// MFMA flash attention. One block per (h=blockIdx.x, b=blockIdx.y), 4 waves.
// Wave w owns Q rows [b*64 + 16w, +16) -> private online softmax, no cross-
// wave state. KV chunk = 64 rows: K staged [64][104] (pad -> 2-way = free),
// V staged transposed Vt[96][72], P converts C-layout -> A-layout via LDS.
// Q pre-LN'd + qk_scale folded; K pre-LN'd.
// ---------------------------------------------------------------------------
__global__ __launch_bounds__(256) void attn_mfma(
    const u16* __restrict__ Q, const u16* __restrict__ Kb,
    const u16* __restrict__ Vb, u16* __restrict__ Res)
{
  __shared__ __align__(16) u16 Ks[64 * 104];
  __shared__ __align__(16) u16 Vt[96 * 72];
  __shared__ __align__(16) u16 Ps[4][16 * 72];
  const int h = blockIdx.x, b = blockIdx.y;
  const int t = threadIdx.x, lane = t & 63, wv = t >> 6;
  const int quad = lane >> 4, rsel = lane & 15;

  // Q A-fragments (3 k-tiles of 32 over d=96)
  bf16x8 aq[3];
  const int qrow0 = b * 64 + wv * 16;
  {
    const u16* qp = Q + (size_t)(qrow0 + rsel) * 1536 + h * 96 + quad * 8;
    aq[0] = *(const bf16x8*)(qp);
    aq[1] = *(const bf16x8*)(qp + 32);
    aq[2] = *(const bf16x8*)(qp + 64);
  }

  f32x4 accO[6] = {};
  float mrow[4] = {-1e30f, -1e30f, -1e30f, -1e30f};
  float lrow[4] = {0.f, 0.f, 0.f, 0.f};

  const size_t kvbase = (size_t)b * 2112 * 1536 + (size_t)h * 96;
  u16* ps = Ps[wv];

  for (int tile = 0; tile < 33; ++tile) {
    __syncthreads();
    // ---- stage K chunk [64][96] -> Ks[64][104] (row-padded) ----
#pragma unroll
    for (int it = 0; it < 3; ++it) {
      const int e0 = (((wv * 3 + it) << 6) + lane) << 3;   // bf16 elem index
      const int j = e0 / 96, d = e0 - j * 96;              // 8 | 96: no straddle
      const u16x8 k8 = *(const u16x8*)(Kb + kvbase + (size_t)(tile * 64 + j) * 1536 + d);
      *(u16x8*)(Ks + j * 104 + d) = k8;
    }
    // ---- stage V chunk transposed -> Vt[96][72] ----
#pragma unroll
    for (int it = 0; it < 3; ++it) {
      const int g = ((wv * 3 + it) << 6) + lane;
      const int kvp = g & 31, dr = g >> 5;                 // dr in 0..23
      const size_t ga = kvbase + (size_t)(tile * 64 + kvp * 2) * 1536 + dr * 4;
      const ushort4 va = *(const ushort4*)(Vb + ga);
      const ushort4 vb4 = *(const ushort4*)(Vb + ga + 1536);
      u32* vt = (u32*)Vt;
      vt[(dr * 4 + 0) * 36 + kvp] = (u32)va.x | ((u32)vb4.x << 16);
      vt[(dr * 4 + 1) * 36 + kvp] = (u32)va.y | ((u32)vb4.y << 16);
      vt[(dr * 4 + 2) * 36 + kvp] = (u32)va.z | ((u32)vb4.z << 16);
      vt[(dr * 4 + 3) * 36 + kvp] = (u32)va.w | ((u32)vb4.w << 16);
    }
    __syncthreads();

    // ---- S = Q * K^T : 4 n-tiles x 3 k-tiles ----
    f32x4 accS[4] = {};
#pragma unroll
    for (int nt = 0; nt < 4; ++nt) {
#pragma unroll
      for (int kt = 0; kt < 3; ++kt) {
        const bf16x8 bk = *(const bf16x8*)(Ks + (nt * 16 + rsel) * 104 + kt * 32 + quad * 8);
        accS[nt] = __builtin_amdgcn_mfma_f32_16x16x32_bf16(aq[kt], bk, accS[nt], 0, 0, 0);
      }
    }

    // ---- online softmax over this chunk (rows = quad*4 + r) ----
    float alpha[4], rs[4];
#pragma unroll
    for (int r = 0; r < 4; ++r) {
      float mt = fmaxf(fmaxf(accS[0][r], accS[1][r]), fmaxf(accS[2][r], accS[3][r]));
      mt = fmaxf(mt, __shfl_xor(mt, 1));
      mt = fmaxf(mt, __shfl_xor(mt, 2));
      mt = fmaxf(mt, __shfl_xor(mt, 4));
      mt = fmaxf(mt, __shfl_xor(mt, 8));
      const float nm = fmaxf(mrow[r], mt);
      alpha[r] = __expf(mrow[r] - nm);
      mrow[r] = nm;
      rs[r] = 0.f;
    }
#pragma unroll
    for (int nt = 0; nt < 4; ++nt)
#pragma unroll
      for (int r = 0; r < 4; ++r) {
        const float p = __expf(accS[nt][r] - mrow[r]);
        accS[nt][r] = p;
        rs[r] += p;
      }
#pragma unroll
    for (int r = 0; r < 4; ++r) {
      rs[r] += __shfl_xor(rs[r], 1);
      rs[r] += __shfl_xor(rs[r], 2);
      rs[r] += __shfl_xor(rs[r], 4);
      rs[r] += __shfl_xor(rs[r], 8);
      lrow[r] = lrow[r] * alpha[r] + rs[r];
    }
#pragma unroll
    for (int nd = 0; nd < 6; ++nd)
#pragma unroll
      for (int r = 0; r < 4; ++r) accO[nd][r] *= alpha[r];

    // ---- P: C-layout -> A-layout via private LDS slab ----
#pragma unroll
    for (int nt = 0; nt < 4; ++nt)
#pragma unroll
      for (int r = 0; r < 4; ++r)
        ps[(quad * 4 + r) * 72 + nt * 16 + rsel] = f2bf(accS[nt][r]);

    // ---- O += P * V : 6 d-tiles x 2 k-tiles ----
#pragma unroll
    for (int kt = 0; kt < 2; ++kt) {
      const bf16x8 ap = *(const bf16x8*)(ps + rsel * 72 + kt * 32 + quad * 8);
#pragma unroll
      for (int nd = 0; nd < 6; ++nd) {
        const bf16x8 bv = *(const bf16x8*)(Vt + (nd * 16 + rsel) * 72 + kt * 32 + quad * 8);
        accO[nd] = __builtin_amdgcn_mfma_f32_16x16x32_bf16(ap, bv, accO[nd], 0, 0, 0);
      }
    }
  }

  float il[4];
#pragma unroll
  for (int r = 0; r < 4; ++r) il[r] = 1.f / lrow[r];
#pragma unroll
  for (int nd = 0; nd < 6; ++nd)
#pragma unroll
    for (int r = 0; r < 4; ++r)
      Res[(size_t)(qrow0 + quad * 4 + r) * 1536 + h * 96 + nd * 16 + rsel] =
          f2bf(accO[nd][r] * il[r]);
}

// ---------------------------------------------------------------------------
extern "C" void kernel_launch(void* const* d_in, const int* in_sizes, int n_in,
                              void* d_out, int out_size, void* d_ws, size_t ws_size,
                              hipStream_t stream) {
  const float* context  = (const float*)d_in[0];
  const float* latents  = (const float*)d_in[1];
  const float* ctx_ln_w = (const float*)d_in[2];
  const float* ctx_ln_b = (const float*)d_in[3];
  const float* lat_ln_w = (const float*)d_in[4];
  const float* lat_ln_b = (const float*)d_in[5];
  const float* q_ln_w   = (const float*)d_in[6];
  const float* q_ln_b   = (const float*)d_in[7];
  const float* k_ln_w   = (const float*)d_in[8];
  const float* k_ln_b   = (const float*)d_in[9];
  const float* wq       = (const float*)d_in[10];
  const float* wk       = (const float*)d_in[11];
  const float* wv       = (const float*)d_in[12];
  const float* wo       = (const float*)d_in[13];
  const float* mlp_ln_w = (const float*)d_in[14];
  const float* mlp_ln_b = (const float*)d_in[15];
  const float* w_fc     = (const float*)d_in[16];
  const float* w_cproj  = (const float*)d_in[17];
  const float* fin_w    = (const float*)d_in[18];
  const float* fin_b    = (const float*)d_in[19];

  char* ws = (char*)d_ws;
  u16*   normctx = (u16*)(ws + 0ull);            // [65536,1280] bf16
  u16*   Kbuf    = (u16*)(ws + 167772160ull);    // [32,2112,1536] bf16
  u16*   Vbuf    = (u16*)(ws + 375390208ull);    // [32,2112,1536] bf16
  float* lat     = (float*)(ws + 583008256ull);  // [2048,1280] f32
  u16*   latn    = (u16*)(ws + 593494016ull);    // [2048,1280] bf16
  u16*   mlpn    = (u16*)(ws + 598736896ull);    // [2048,1280] bf16
  u16*   qb      = (u16*)(ws + 603979776ull);    // [2048,1536] bf16
  u16*   res     = (u16*)(ws + 610271232ull);    // [2048,1536] bf16
  u16*   hb      = (u16*)(ws + 616562688ull);    // [2048,5120] bf16
  u16*   wT      = (u16*)(ws + 637534208ull);    // transposed weights
  float* biaskv  = (float*)(ws + 687341568ull);  // [3072]

  u16* wqT   = wT;                   // [1536,1280]
  u16* wkvT  = wT + 1966080;         // [3072,1280] (k then v, unfolded)
  u16* wkvfT = wT + 5898240;         // [3072,1280] (k then v, ctx_ln_w folded)
  u16* woT   = wT + 9830400;         // [1280,1536]
  u16* wfcT  = wT + 11796480;        // [5120,1280]
  u16* wcpT  = wT + 18350080;        // [1280,5120]

  const float qscale = 1.0f / sqrtf(96.0f);

  // norm(context) once: layer-invariant (ctx LN w/b folded into weights/bias)
  ln_rows<u16><<<65536, 320, 0, stream>>>(context, normctx, nullptr, nullptr);
  lat_init<<<2048, 320, 0, stream>>>(latents, lat);

  for (int i = 0; i < 3; ++i) {
    transcast<<<dim3(48, 40), 256, 0, stream>>>(wq + (size_t)i * 1966080, wqT, nullptr, 1280, 1536);
    transcast<<<dim3(48, 40), 256, 0, stream>>>(wk + (size_t)i * 1966080, wkvT, nullptr, 1280, 1536);
    transcast<<<dim3(48, 40), 256, 0, stream>>>(wv + (size_t)i * 1966080, wkvT + 1966080, nullptr, 1280, 1536);
    transcast<<<dim3(48, 40), 256, 0, stream>>>(wk + (size_t)i * 1966080, wkvfT, ctx_ln_w + i * 1280, 1280, 1536);
    transcast<<<dim3(48, 40), 256, 0, stream>>>(wv + (size_t)i * 1966080, wkvfT + 1966080, ctx_ln_w + i * 1280, 1280, 1536);
    transcast<<<dim3(40, 48), 256, 0, stream>>>(wo + (size_t)i * 1966080, woT, nullptr, 1536, 1280);
    transcast<<<dim3(160, 40), 256, 0, stream>>>(w_fc + (size_t)i * 6553600, wfcT, nullptr, 1280, 5120);
    transcast<<<dim3(40, 160), 256, 0, stream>>>(w_cproj + (size_t)i * 6553600, wcpT, nullptr, 5120, 1280);
    bias_dot<<<3072, 64, 0, stream>>>(wkvT, ctx_ln_b + i * 1280, biaskv, 1280);

    ln_rows<u16><<<2048, 320, 0, stream>>>(lat, latn, lat_ln_w + i * 1280, lat_ln_b + i * 1280);

    // K/V fused: ctx rows (b*2112+s) and latent rows (b*2112+2048+n)
    gemm_bf16<<<dim3(24, 512), 256, 0, stream>>>(normctx, wkvfT, Kbuf, Vbuf, biaskv, nullptr,
        65536, 3072, 1536, 1280, 11, 2112, 0, 1 | 4);
    gemm_bf16<<<dim3(24, 16), 256, 0, stream>>>(latn, wkvT, Kbuf, Vbuf, nullptr, nullptr,
        2048, 3072, 1536, 1280, 6, 2112, 2048, 1 | 4);
    // Q
    gemm_bf16<<<dim3(12, 16), 256, 0, stream>>>(latn, wqT, qb, nullptr, nullptr, nullptr,
        2048, 1536, 1536, 1280, 11, 2048, 0, 1);

    // per-head LN on q (qk_scale folded) and k
    seg_ln<<<8192, 256, 0, stream>>>(qb, q_ln_w + i * 96, q_ln_b + i * 96, qscale, 32768);
    seg_ln<<<270336, 256, 0, stream>>>(Kbuf, k_ln_w + i * 96, k_ln_b + i * 96, 1.0f, 1081344);

    attn_mfma<<<dim3(16, 32), 256, 0, stream>>>(qb, Kbuf, Vbuf, res);

    // lat = res @ wo + lat
    gemm_bf16<<<dim3(10, 16), 256, 0, stream>>>(res, woT, lat, nullptr, nullptr, lat,
        2048, 1280, 1280, 1536, 11, 2048, 0, 0);

    // MLP
    ln_rows<u16><<<2048, 320, 0, stream>>>(lat, mlpn, mlp_ln_w + i * 1280, mlp_ln_b + i * 1280);
    gemm_bf16<<<dim3(40, 16), 256, 0, stream>>>(mlpn, wfcT, hb, nullptr, nullptr, nullptr,
        2048, 5120, 5120, 1280, 11, 2048, 0, 1 | 2);
    gemm_bf16<<<dim3(10, 16), 256, 0, stream>>>(hb, wcpT, lat, nullptr, nullptr, lat,
        2048, 1280, 1280, 5120, 11, 2048, 0, 0);
  }

  ln_rows<float><<<2048, 320, 0, stream>>>(lat, (float*)d_out, fin_w, fin_b);
}